// Round 2
// baseline (337.431 us; speedup 1.0000x reference)
//
#include <hip/hip_runtime.h>

#define HID 256
#define K27 27

typedef __attribute__((ext_vector_type(8))) short bf16x8;
typedef __attribute__((ext_vector_type(4))) float f32x4;

// fp32 -> bf16 bits, round-to-nearest-even
static __device__ __forceinline__ short f2bf(float f) {
    union { float f; unsigned u; } v; v.f = f;
    unsigned r = (v.u + 0x7FFFu + ((v.u >> 16) & 1u)) >> 16;
    return (short)r;
}

// v2: layer-2 as MFMA (16x16x32 bf16), layer-1 h computed in A-fragment
// layout, gather-dot distributed over 16 lanes/pixel + shfl_xor reduce.
// k-map inside a 32-chunk: element i of lane-group g <-> j = kc*32 + g + 4*i
// (same map used for A and B, so the contraction is correct regardless of the
// hardware's internal k ordering; it also makes the 4 groups' sW1 rows land
// in distinct LDS banks -> conflict-free broadcast reads).
__global__ __launch_bounds__(256) void mapnet_mfma(
    const float* __restrict__ pos,      // (P,3)
    const int*   __restrict__ mapping,  // (P,2)
    const float* __restrict__ feats,    // (3,512,512)
    const float* __restrict__ W1,       // (256,3)
    const float* __restrict__ b1,       // (256)
    const float* __restrict__ W2,       // (27,256)
    const float* __restrict__ b2,       // (27)
    float* __restrict__ out,            // (P)
    int ntiles)
{
    __shared__ float sW1[HID][4];       // {w0,w1,w2,b1}, 16B rows
    const int tid = threadIdx.x;
    for (int i = tid; i < HID; i += 256) {
        sW1[i][0] = W1[3*i+0]; sW1[i][1] = W1[3*i+1];
        sW1[i][2] = W1[3*i+2]; sW1[i][3] = b1[i];
    }
    __syncthreads();

    const int lane = tid & 63;
    const int wid  = tid >> 6;
    const int g    = lane >> 4;     // lane group 0..3
    const int col  = lane & 15;     // A-row pixel idx / C-col (k27) idx

    // ---- B fragments: W2^T in bf16, resident in registers ----
    bf16x8 Bf[8][2];
    #pragma unroll
    for (int kc = 0; kc < 8; ++kc) {
        #pragma unroll
        for (int nt = 0; nt < 2; ++nt) {
            const int n = nt*16 + col;
            bf16x8 bb;
            #pragma unroll
            for (int i = 0; i < 8; ++i) {
                const int j = kc*32 + g + 4*i;
                const float w = (n < K27) ? W2[n*HID + j] : 0.0f;
                bb[i] = f2bf(w);
            }
            Bf[kc][nt] = bb;
        }
    }
    const float b2A = b2[col];                                  // col < 16 < 27
    const float b2B = (16 + col < K27) ? b2[16 + col] : 0.0f;

    // this lane's two k27 columns -> (c, dy, dx) gather constants
    const int kA = col, kB = 16 + col;
    const int cA = kA / 9, rA = kA % 9, dyA = rA / 3, dxA = rA % 3;
    const int cB = kB / 9, rB = kB % 9, dyB = rB / 3, dxB = rB % 3;

    const int nwaves = gridDim.x * 4;
    for (int t = blockIdx.x * 4 + wid; t < ntiles; t += nwaves) {
        const int tbase = t * 16;

        // layer-1 inputs for this lane's A-row pixel
        const int pA = tbase + col;
        const float p0 = pos[3*pA+0], p1 = pos[3*pA+1], p2 = pos[3*pA+2];

        f32x4 acc0 = {b2A, b2A, b2A, b2A};
        f32x4 acc1 = {b2B, b2B, b2B, b2B};

        #pragma unroll
        for (int kc = 0; kc < 8; ++kc) {
            bf16x8 a;
            #pragma unroll
            for (int i = 0; i < 8; ++i) {
                const int j = kc*32 + g + 4*i;
                const float4 w = *reinterpret_cast<const float4*>(&sW1[j][0]);
                float x = fmaf(p0, w.x, fmaf(p1, w.y, fmaf(p2, w.z, w.w)));
                x = fmaxf(x, 0.01f * x);      // leaky_relu(0.01)
                a[i] = f2bf(x);
            }
            acc0 = __builtin_amdgcn_mfma_f32_16x16x32_bf16(a, Bf[kc][0], acc0, 0, 0, 0);
            acc1 = __builtin_amdgcn_mfma_f32_16x16x32_bf16(a, Bf[kc][1], acc1, 0, 0, 0);
        }

        // ---- gather + dot; C/D layout: col = lane&15, row = g*4 + r ----
        #pragma unroll
        for (int r = 0; r < 4; ++r) {
            const int m  = tbase + g*4 + r;
            const int my = mapping[2*m+0];
            const int mx = mapping[2*m+1];

            int y = my + dyA - 1, x = mx + dxA - 1;
            int yc = min(max(y,0),511), xc = min(max(x,0),511);
            float fv = feats[(cA*512+yc)*512+xc];
            fv = (((unsigned)y < 512u) && ((unsigned)x < 512u)) ? fv : 0.0f;
            float s = acc0[r] * fv;

            if (kB < K27) {
                int y2 = my + dyB - 1, x2 = mx + dxB - 1;
                int yc2 = min(max(y2,0),511), xc2 = min(max(x2,0),511);
                float f2 = feats[(cB*512+yc2)*512+xc2];
                f2 = (((unsigned)y2 < 512u) && ((unsigned)x2 < 512u)) ? f2 : 0.0f;
                s = fmaf(acc1[r], f2, s);
            }

            // reduce over the 16 lanes of this group (k dimension)
            s += __shfl_xor(s, 1);
            s += __shfl_xor(s, 2);
            s += __shfl_xor(s, 4);
            s += __shfl_xor(s, 8);
            if (col == r) out[m] = s;
        }
    }
}

extern "C" void kernel_launch(void* const* d_in, const int* in_sizes, int n_in,
                              void* d_out, int out_size, void* d_ws, size_t ws_size,
                              hipStream_t stream) {
    const float* pos     = (const float*)d_in[0];
    const int*   mapping = (const int*)d_in[1];
    const float* feats   = (const float*)d_in[2];
    // d_in[3] = depth, unused
    const float* W1      = (const float*)d_in[4];
    const float* b1      = (const float*)d_in[5];
    const float* W2      = (const float*)d_in[6];
    const float* b2      = (const float*)d_in[7];
    float* out = (float*)d_out;

    const int P = out_size;          // 1024*1024, divisible by 16
    const int ntiles = P / 16;
    const int blocks = 2048;         // 8192 waves, 8 tiles each
    mapnet_mfma<<<blocks, 256, 0, stream>>>(pos, mapping, feats, W1, b1, W2, b2, out, ntiles);
}